// Round 6
// baseline (361.759 us; speedup 1.0000x reference)
//
#include <hip/hip_runtime.h>

// GCN 2-layer: per layer h = X@W; out[i] = b + dinv[i]^2*h[i] + sum_{e:dst=i} dinv[src]*dinv[i]*h[src]
// N=100000 nodes, E=1200000 edges, C=64 channels, fp32 throughout.
// R6: norm refactor — sum dinv[s]*dinv[d]*h[s] = dinv[d] * sum (dinv[s]*h[s]).
//     dinv[src] folded into gemm epilogue (h' = dinv ⊙ X@W); dinv[dst] applied once
//     per node in aggregate. CSR payload shrinks to 4 B/edge (src only): the 4.8 MB
//     bucket region ~fits per-XCD L2, cutting scatter's 78 MB HBM writeback
//     (R5 evidence: 8 B/edge random stores -> 64 B line dirtied each -> 60 us).

#define NCH 64
#define XS_STRIDE 68  // 64 + 4 pad: keeps b128 16B alignment; 4-row spacing -> bank+16 (2-way, free)

// counts[d] = #edges with dst==d
__global__ void hist_kernel(const int* __restrict__ dst, int* __restrict__ counts, int E) {
    int e = blockIdx.x * blockDim.x + threadIdx.x;
    if (e < E) atomicAdd(&counts[dst[e]], 1);
}

// ---------------- exclusive scan (3-phase), chunk = 1024; dinv fused ----------------
__global__ __launch_bounds__(256) void scanA_kernel(const int* __restrict__ counts,
                                                    int* __restrict__ rowp,
                                                    int* __restrict__ bsums,
                                                    float* __restrict__ dinv, int n) {
    __shared__ int sh[256];
    int tid = threadIdx.x;
    int base = blockIdx.x * 1024;
    int v[4];
    int ts = 0;
#pragma unroll
    for (int j = 0; j < 4; j++) {
        int idx = base + tid * 4 + j;
        int c = (idx < n) ? counts[idx] : 0;
        v[j] = c; ts += c;
        if (idx < n) dinv[idx] = rsqrtf((float)(c + 1));  // +1 self loop
    }
    sh[tid] = ts; __syncthreads();
    for (int off = 1; off < 256; off <<= 1) {
        int t = (tid >= off) ? sh[tid - off] : 0;
        __syncthreads();
        sh[tid] += t;
        __syncthreads();
    }
    int run = sh[tid] - ts;  // exclusive offset within chunk
#pragma unroll
    for (int j = 0; j < 4; j++) {
        run += v[j];
        int idx = base + tid * 4 + j;
        if (idx < n) rowp[idx + 1] = run;  // inclusive-within-chunk at [idx+1]
    }
    if (tid == 255) bsums[blockIdx.x] = sh[255];
}

__global__ __launch_bounds__(128) void scanB_kernel(int* __restrict__ bsums, int nb) {
    __shared__ int sh[128];
    int tid = threadIdx.x;
    int v = (tid < nb) ? bsums[tid] : 0;
    sh[tid] = v; __syncthreads();
    for (int off = 1; off < 128; off <<= 1) {
        int t = (tid >= off) ? sh[tid - off] : 0;
        __syncthreads();
        sh[tid] += t;
        __syncthreads();
    }
    if (tid < nb) bsums[tid] = sh[tid] - v;  // exclusive chunk offsets
}

__global__ void scanC_kernel(int* __restrict__ rowp, const int* __restrict__ bsums, int n) {
    int i = blockIdx.x * blockDim.x + threadIdx.x;
    if (i < n) {
        rowp[i + 1] += bsums[i >> 10];
        if (i == 0) rowp[0] = 0;
    }
}

// scatter edges into CSR buckets — 4 B (src only) per edge
__global__ void scatter_kernel(const int* __restrict__ src, const int* __restrict__ dst,
                               const int* __restrict__ rowp, int* __restrict__ cursor,
                               int* __restrict__ csrc, int E) {
    int e = blockIdx.x * blockDim.x + threadIdx.x;
    if (e < E) {
        int d = dst[e];
        int pos = rowp[d] + atomicAdd(&cursor[d], 1);
        csrc[pos] = src[e];
    }
}

// ---------------- H = dinv ⊙ (X @ W)  (K=64, fp32 VALU) ----------------
// 64x64 tile per block; 256 threads as 16x16; each thread: 4 rows x 4 cols (16 acc).
// k-loop unroll capped at 2: full unroll hoists all 32 ds_read_b128 -> 256 VGPR
// (R4 evidence); unroll 2 keeps live set ~100 VGPR.
// Epilogue scales row i by dscale[row] (folds dinv[src] into h).
__global__ __launch_bounds__(256) void gemm64_kernel(const float* __restrict__ X,
                                                     const float* __restrict__ W,
                                                     const float* __restrict__ dscale,
                                                     float* __restrict__ H, int nrows) {
    __shared__ float Xs[64 * XS_STRIDE];
    __shared__ float Ws[64 * 64];
    int tid = threadIdx.x;
    int row0 = blockIdx.x * 64;

    // stage W (4096 floats): 4 float4/thread, coalesced
    {
        const float4* W4 = (const float4*)W;
#pragma unroll
        for (int i = 0; i < 4; i++) {
            int idx = tid + 256 * i;           // float4 index
            float4 v = W4[idx];
            int r = idx >> 4, kc = (idx & 15) << 2;
            *(float4*)&Ws[r * 64 + kc] = v;
        }
    }
    // stage X tile (64 rows x 64): 4 float4/thread, coalesced; padded stride in LDS
    {
        const float4* X4 = (const float4*)(X + (size_t)row0 * NCH);
#pragma unroll
        for (int i = 0; i < 4; i++) {
            int idx = tid + 256 * i;
            int r = idx >> 4, kc = (idx & 15) << 2;
            if (row0 + r < nrows)
                *(float4*)&Xs[r * XS_STRIDE + kc] = X4[idx];
        }
    }
    __syncthreads();

    int c  = (tid & 15) << 2;   // col base
    int r0 = (tid >> 4) << 2;   // block-local row base

    float4 acc[4];
#pragma unroll
    for (int i = 0; i < 4; i++) acc[i] = make_float4(0.f, 0.f, 0.f, 0.f);

#pragma unroll 2
    for (int k4 = 0; k4 < 16; k4++) {
        float4 wv[4], xv[4];
#pragma unroll
        for (int j = 0; j < 4; j++) wv[j] = *(const float4*)&Ws[(k4 * 4 + j) * 64 + c];
#pragma unroll
        for (int i = 0; i < 4; i++) xv[i] = *(const float4*)&Xs[(r0 + i) * XS_STRIDE + k4 * 4];
#pragma unroll
        for (int i = 0; i < 4; i++) {
            acc[i].x += xv[i].x * wv[0].x + xv[i].y * wv[1].x + xv[i].z * wv[2].x + xv[i].w * wv[3].x;
            acc[i].y += xv[i].x * wv[0].y + xv[i].y * wv[1].y + xv[i].z * wv[2].y + xv[i].w * wv[3].y;
            acc[i].z += xv[i].x * wv[0].z + xv[i].y * wv[1].z + xv[i].z * wv[2].z + xv[i].w * wv[3].z;
            acc[i].w += xv[i].x * wv[0].w + xv[i].y * wv[1].w + xv[i].z * wv[2].w + xv[i].w * wv[3].w;
        }
    }

#pragma unroll
    for (int i = 0; i < 4; i++) {
        int row = row0 + r0 + i;
        if (row < nrows) {
            float ds = dscale[row];
            acc[i].x *= ds; acc[i].y *= ds; acc[i].z *= ds; acc[i].w *= ds;
            *(float4*)&H[(size_t)row * NCH + c] = acc[i];
        }
    }
}

// ---------------- gather-aggregate: wave per node, lane per channel ----------------
// H is pre-scaled by dinv[src]; out = b + dinv[node]*(H[node] + sum H[csrc[e]])
// 8 outstanding gathers (latency-bound loop; mean degree 12 -> one 8-batch + one 4-batch)
__global__ __launch_bounds__(256) void aggregate_kernel(const float* __restrict__ H,
                                                        const int* __restrict__ rowp,
                                                        const int* __restrict__ csrc,
                                                        const float* __restrict__ dinv,
                                                        const float* __restrict__ bias,
                                                        float* __restrict__ out,
                                                        int n, int do_relu) {
    int node = blockIdx.x * 4 + (threadIdx.x >> 6);
    int lane = threadIdx.x & 63;
    if (node >= n) return;
    float a0 = H[(size_t)node * NCH + lane];  // self loop (dinv[node] applied at end)
    float a1 = 0.f, a2 = 0.f, a3 = 0.f;
    float a4 = 0.f, a5 = 0.f, a6 = 0.f, a7 = 0.f;
    int e = rowp[node];
    int end = rowp[node + 1];
    for (; e + 7 < end; e += 8) {
        int s0 = csrc[e];
        int s1 = csrc[e + 1];
        int s2 = csrc[e + 2];
        int s3 = csrc[e + 3];
        int s4 = csrc[e + 4];
        int s5 = csrc[e + 5];
        int s6 = csrc[e + 6];
        int s7 = csrc[e + 7];
        a0 += H[(size_t)s0 * NCH + lane];
        a1 += H[(size_t)s1 * NCH + lane];
        a2 += H[(size_t)s2 * NCH + lane];
        a3 += H[(size_t)s3 * NCH + lane];
        a4 += H[(size_t)s4 * NCH + lane];
        a5 += H[(size_t)s5 * NCH + lane];
        a6 += H[(size_t)s6 * NCH + lane];
        a7 += H[(size_t)s7 * NCH + lane];
    }
    if (e + 3 < end) {
        int s0 = csrc[e];
        int s1 = csrc[e + 1];
        int s2 = csrc[e + 2];
        int s3 = csrc[e + 3];
        a0 += H[(size_t)s0 * NCH + lane];
        a1 += H[(size_t)s1 * NCH + lane];
        a2 += H[(size_t)s2 * NCH + lane];
        a3 += H[(size_t)s3 * NCH + lane];
        e += 4;
    }
    for (; e < end; e++) {
        a0 += H[(size_t)csrc[e] * NCH + lane];
    }
    float sum = ((a0 + a1) + (a2 + a3)) + ((a4 + a5) + (a6 + a7));
    float acc = bias[lane] + dinv[node] * sum;
    if (do_relu) acc = fmaxf(acc, 0.f);
    out[(size_t)node * NCH + lane] = acc;
}

extern "C" void kernel_launch(void* const* d_in, const int* in_sizes, int n_in,
                              void* d_out, int out_size, void* d_ws, size_t ws_size,
                              hipStream_t stream) {
    const float* x  = (const float*)d_in[0];
    const int* edge = (const int*)d_in[1];
    const float* W1 = (const float*)d_in[2];
    const float* b1 = (const float*)d_in[3];
    const float* W2 = (const float*)d_in[4];
    const float* b2 = (const float*)d_in[5];
    float* out = (float*)d_out;

    const int N = in_sizes[0] / NCH;       // 100000
    const int E = in_sizes[1] / 2;         // 1200000
    const int* src = edge;
    const int* dst = edge + E;

    // workspace layout (16B-aligned blocks)
    char* w = (char*)d_ws;
    const size_t SZN = 400128;             // >= (N+1)*4, padded
    int*   counts = (int*)(w + 0);
    int*   cursor = (int*)(w + SZN);
    int*   rowp   = (int*)(w + 2 * SZN);   // N+1 ints
    float* dinv   = (float*)(w + 3 * SZN);
    int*   bsums  = (int*)(w + 4 * SZN);   // 128 ints
    int*   csrc   = (int*)(w + 4 * SZN + 512);                // E ints = 4.8 MB
    float* h      = (float*)(w + 4 * SZN + 512 + (size_t)E * 4);  // N*64 floats

    const int NB_SCAN = (N + 1023) / 1024;  // 98

    // 1) zero counts + cursor (contiguous 2*SZN bytes)
    hipMemsetAsync(counts, 0, 2 * SZN, stream);
    // 2) degree histogram over dst
    hist_kernel<<<(E + 255) / 256, 256, 0, stream>>>(dst, counts, E);
    // 3-5) exclusive scan counts -> rowp (dinv fused into scanA)
    scanA_kernel<<<NB_SCAN, 256, 0, stream>>>(counts, rowp, bsums, dinv, N);
    scanB_kernel<<<1, 128, 0, stream>>>(bsums, NB_SCAN);
    scanC_kernel<<<(N + 255) / 256, 256, 0, stream>>>(rowp, bsums, N);
    // 6) scatter src ids into CSR
    scatter_kernel<<<(E + 255) / 256, 256, 0, stream>>>(src, dst, rowp, cursor, csrc, E);

    const int GB = (N + 63) / 64;      // gemm blocks (64 rows each)
    const int AB = (N + 3) / 4;        // aggregate blocks (4 waves/block)

    // Layer 1: h = dinv ⊙ (x@W1) ; d_out = relu(b1 + dinv ⊙ gather-sum(h))
    gemm64_kernel<<<GB, 256, 0, stream>>>(x, W1, dinv, h, N);
    aggregate_kernel<<<AB, 256, 0, stream>>>(h, rowp, csrc, dinv, b1, out, N, 1);
    // Layer 2: same with W2/b2, no relu
    gemm64_kernel<<<GB, 256, 0, stream>>>(out, W2, dinv, h, N);
    aggregate_kernel<<<AB, 256, 0, stream>>>(h, rowp, csrc, dinv, b2, out, N, 0);
}